// Round 4
// baseline (229.117 us; speedup 1.0000x reference)
//
#include <hip/hip_runtime.h>
#include <hip/hip_fp16.h>

// Problem constants: x (1,64,8,56,56), offset (1,648,8,56,56),
// weight (64,64,3,3,3), stride=1, pad=1, cpg=8.
namespace {
constexpr int D_ = 8, H_ = 56, W_ = 56;
constexpr int HW_ = H_ * W_;
constexpr int KV_ = 27;
constexpr int N_ = D_ * H_ * W_;   // 25088
constexpr int NT_ = 16;            // n-cols per block (one MFMA n-tile)
constexpr int NBLK_ = N_ / NT_;    // 1568
}

typedef _Float16 f16x8 __attribute__((ext_vector_type(8)));
typedef float f32x4 __attribute__((ext_vector_type(4)));

union U4H { uint4 u; __half2 h[4]; f16x8 v; };

// prep: xt[g][n][8] f16   and   wt[kv][kc(8)][o(64)][8] f16 (A-frag coalesced)
__global__ __launch_bounds__(256) void prep_kernel(const float* __restrict__ x,
                                                   const float* __restrict__ w,
                                                   __half* __restrict__ xt,
                                                   __half* __restrict__ wt) {
    const int b = blockIdx.x, tid = threadIdx.x;
    if (b < 784) {
        const int g = b / 98;
        const int n = (b % 98) * 256 + tid;
        U4H p;
#pragma unroll
        for (int cc = 0; cc < 4; ++cc) {
            float lo = x[(g * 8 + 2 * cc) * N_ + n];
            float hi = x[(g * 8 + 2 * cc + 1) * N_ + n];
            p.h[cc] = __floats2half2_rn(lo, hi);
        }
        *(uint4*)(xt + ((size_t)g * N_ + n) * 8) = p.u;
    } else {
        const int idx = (b - 784) * 256 + tid;   // < 110592
        const int kv = idx % 27;
        const int oc = idx / 27;                 // o*64 + c
        const int c = oc & 63, o = oc >> 6;
        const int kc = c >> 3, e = c & 7;
        wt[kv * 4096 + kc * 512 + o * 8 + e] = __float2half(w[oc * 27 + kv]);
    }
}

__global__ __launch_bounds__(256) void dconv_kernel(const float* __restrict__ offset,
                                                    const __half* __restrict__ xt,
                                                    const __half* __restrict__ wt,
                                                    float* __restrict__ out) {
    __shared__ __half val_s[4][NT_ * 64];   // per-wave [nl][c], XOR-swizzled (2KB each)
    __shared__ float red_s[4][64 * NT_];    // per-wave partial C tiles (16KB)
    const int tid = threadIdx.x;
    const int lane = tid & 63;
    const int wv = tid >> 6;
    const int n0 = blockIdx.x * NT_;

    // kv split across the 4 waves: 7,7,7,6
    const int kvn = (wv == 3) ? 6 : 7;
    const int kv0 = wv * 7;

    // two sampling tasks per lane: task = (g, nl)
    int t_g[2], t_nl[2], t_zo[2], t_yo[2], t_xo[2], t_ob[2];
#pragma unroll
    for (int ph = 0; ph < 2; ++ph) {
        int task = ph * 64 + lane;
        int g = task >> 4, nl = task & 15;
        int n = n0 + nl;
        int zo = n / HW_, rem = n - zo * HW_;
        int yo = rem / W_, xo = rem - yo * W_;
        t_g[ph] = g; t_nl[ph] = nl;
        t_zo[ph] = zo; t_yo[ph] = yo; t_xo[ph] = xo;
        t_ob[ph] = g * (KV_ * 3 * N_) + n;
    }

    f32x4 acc[4] = {};

    // offset prefetch (one kv ahead)
    float oz[2], oy[2], ox[2];
#pragma unroll
    for (int ph = 0; ph < 2; ++ph) {
        const float* p = offset + t_ob[ph] + kv0 * 3 * N_;
        oz[ph] = p[0]; oy[ph] = p[N_]; ox[ph] = p[2 * N_];
    }

    for (int kvi = 0; kvi < kvn; ++kvi) {
        const int kv = kv0 + kvi;
        const int kz = kv / 9, ky = (kv / 3) % 3, kx = kv % 3;

        float nz[2] = {0.f, 0.f}, ny[2] = {0.f, 0.f}, nxo[2] = {0.f, 0.f};
        if (kvi + 1 < kvn) {
#pragma unroll
            for (int ph = 0; ph < 2; ++ph) {
                const float* p = offset + t_ob[ph] + (kv + 1) * 3 * N_;
                nz[ph] = p[0]; ny[ph] = p[N_]; nxo[ph] = p[2 * N_];
            }
        }

        // ---- sampling: fill this wave's val_s slice for kv ----
#pragma unroll
        for (int ph = 0; ph < 2; ++ph) {
            const int g = t_g[ph];
            float zc = (float)(t_zo[ph] + kz - 1) + oz[ph];
            float yc = (float)(t_yo[ph] + ky - 1) + oy[ph];
            float xc = (float)(t_xo[ph] + kx - 1) + ox[ph];
            float zf = floorf(zc), yf = floorf(yc), xf = floorf(xc);
            float dz = zc - zf, dy = yc - yf, dx = xc - xf;
            int z0 = (int)zf, y0 = (int)yf, x0 = (int)xf;
            int z1 = z0 + 1, y1 = y0 + 1, x1 = x0 + 1;
            float wz0 = (1.f - dz) * ((unsigned)z0 < (unsigned)D_ ? 1.f : 0.f);
            float wz1 = dz * ((unsigned)z1 < (unsigned)D_ ? 1.f : 0.f);
            float wy0 = (1.f - dy) * ((unsigned)y0 < (unsigned)H_ ? 1.f : 0.f);
            float wy1 = dy * ((unsigned)y1 < (unsigned)H_ ? 1.f : 0.f);
            float wx0 = (1.f - dx) * ((unsigned)x0 < (unsigned)W_ ? 1.f : 0.f);
            float wx1 = dx * ((unsigned)x1 < (unsigned)W_ ? 1.f : 0.f);
            int z0c = min(max(z0, 0), D_ - 1), z1c = min(max(z1, 0), D_ - 1);
            int y0c = min(max(y0, 0), H_ - 1), y1c = min(max(y1, 0), H_ - 1);
            int x0c = min(max(x0, 0), W_ - 1), x1c = min(max(x1, 0), W_ - 1);
            const uint4* xg = (const uint4*)(xt + (size_t)g * N_ * 8);
            int zy00 = z0c * HW_ + y0c * W_, zy01 = z0c * HW_ + y1c * W_;
            int zy10 = z1c * HW_ + y0c * W_, zy11 = z1c * HW_ + y1c * W_;
            U4H a; a.u = make_uint4(0u, 0u, 0u, 0u);
#define CORNER(ZY, XC, WF) do { \
                U4H d_; d_.u = xg[(ZY) + (XC)]; \
                __half2 w2_ = __float2half2_rn(WF); \
                a.h[0] = __hfma2(d_.h[0], w2_, a.h[0]); \
                a.h[1] = __hfma2(d_.h[1], w2_, a.h[1]); \
                a.h[2] = __hfma2(d_.h[2], w2_, a.h[2]); \
                a.h[3] = __hfma2(d_.h[3], w2_, a.h[3]); \
            } while (0)
            CORNER(zy00, x0c, wz0 * wy0 * wx0);
            CORNER(zy00, x1c, wz0 * wy0 * wx1);
            CORNER(zy01, x0c, wz0 * wy1 * wx0);
            CORNER(zy01, x1c, wz0 * wy1 * wx1);
            CORNER(zy10, x0c, wz1 * wy0 * wx0);
            CORNER(zy10, x1c, wz1 * wy0 * wx1);
            CORNER(zy11, x0c, wz1 * wy1 * wx0);
            CORNER(zy11, x1c, wz1 * wy1 * wx1);
#undef CORNER
            int byte = (t_nl[ph] * 128 + g * 16) ^ ((t_nl[ph] & 7) << 4);
            *(uint4*)((char*)val_s[wv] + byte) = a.u;
        }

        // ---- MFMA: acc[o 64][n 16] += w[o][c] * val[c][n], K=64 (2 halves) ----
        const int nl = lane & 15;
#pragma unroll
        for (int ks = 0; ks < 2; ++ks) {
            const int c2 = ks * 64 + (lane >> 4) * 16;                 // byte col offset
            const int bbyte = (nl * 128 + c2) ^ ((nl & 7) << 4);
            f16x8 bfrag = *(const f16x8*)((const char*)val_s[wv] + bbyte);
            const char* wbase = (const char*)(wt + kv * 4096);
            const int kc = ks * 4 + (lane >> 4);
#pragma unroll
            for (int of = 0; of < 4; ++of) {
                f16x8 afrag = *(const f16x8*)(wbase + kc * 1024 + (of * 16 + nl) * 16);
                acc[of] = __builtin_amdgcn_mfma_f32_16x16x32_f16(afrag, bfrag, acc[of], 0, 0, 0);
            }
        }

#pragma unroll
        for (int ph = 0; ph < 2; ++ph) { oz[ph] = nz[ph]; oy[ph] = ny[ph]; ox[ph] = nxo[ph]; }
    }

    // ---- combine the 4 waves' partial C tiles via LDS ----
#pragma unroll
    for (int of = 0; of < 4; ++of)
#pragma unroll
        for (int r = 0; r < 4; ++r)
            red_s[wv][(of * 16 + (lane >> 4) * 4 + r) * 16 + (lane & 15)] = acc[of][r];
    __syncthreads();
    f32x4 s = ((const f32x4*)red_s[0])[tid] + ((const f32x4*)red_s[1])[tid]
            + ((const f32x4*)red_s[2])[tid] + ((const f32x4*)red_s[3])[tid];
    const int o = tid >> 2, nw = (tid & 3) * 4;
    *(f32x4*)(out + (size_t)o * N_ + n0 + nw) = s;
}

extern "C" void kernel_launch(void* const* d_in, const int* in_sizes, int n_in,
                              void* d_out, int out_size, void* d_ws, size_t ws_size,
                              hipStream_t stream) {
    const float* x      = (const float*)d_in[0];
    const float* offset = (const float*)d_in[1];
    const float* weight = (const float*)d_in[2];
    float* out = (float*)d_out;

    __half* xt = (__half*)d_ws;                 // 8*25088*8 halves = 3.2 MB
    __half* wt = xt + (size_t)8 * N_ * 8;       // 27*4096 halves = 216 KB

    prep_kernel<<<784 + 432, 256, 0, stream>>>(x, weight, xt, wt);
    dconv_kernel<<<NBLK_, 256, 0, stream>>>(offset, xt, wt, out);
}

// Round 5
// 225.912 us; speedup vs baseline: 1.0142x; 1.0142x over previous
//
#include <hip/hip_runtime.h>
#include <hip/hip_fp16.h>

// Problem constants: x (1,64,8,56,56), offset (1,648,8,56,56),
// weight (64,64,3,3,3), stride=1, pad=1, cpg=8.
namespace {
constexpr int D_ = 8, H_ = 56, W_ = 56;
constexpr int HW_ = H_ * W_;
constexpr int KV_ = 27;
constexpr int N_ = D_ * H_ * W_;    // 25088
constexpr int NT_ = 16;             // n-cols per tile (one MFMA n-dim)
constexpr int NTILES_ = N_ / NT_;   // 1568 = 8 * 196
}

typedef _Float16 f16x8 __attribute__((ext_vector_type(8)));
typedef float f32x4 __attribute__((ext_vector_type(4)));

union U4H { uint4 u; __half2 h[4]; f16x8 v; };

// prep: xt[g][n][8] f16  and  wt2[kv][of][ks][lane][8] f16
//   wt2[kv][of][ks][l][e] = w[o = of*16 + (l&15)][c = ks*32 + (l>>4)*8 + e]
// so each MFMA A-fragment is a contiguous, lane-ordered 1KB wave load.
__global__ __launch_bounds__(256) void prep_kernel(const float* __restrict__ x,
                                                   const float* __restrict__ w,
                                                   __half* __restrict__ xt,
                                                   __half* __restrict__ wt2) {
    const int b = blockIdx.x, tid = threadIdx.x;
    if (b < 784) {
        const int g = b / 98;
        const int n = (b % 98) * 256 + tid;
        U4H p;
#pragma unroll
        for (int cc = 0; cc < 4; ++cc) {
            float lo = x[(size_t)(g * 8 + 2 * cc) * N_ + n];
            float hi = x[(size_t)(g * 8 + 2 * cc + 1) * N_ + n];
            p.h[cc] = __floats2half2_rn(lo, hi);
        }
        *(uint4*)(xt + ((size_t)g * N_ + n) * 8) = p.u;
    } else {
        const int idx = (b - 784) * 256 + tid;    // 0 .. 110591
        const int e  = idx & 7;
        const int l  = (idx >> 3) & 63;
        const int ks = (idx >> 9) & 1;
        const int of = (idx >> 10) & 3;
        const int kv = idx >> 12;                 // 0..26
        const int o = of * 16 + (l & 15);
        const int c = ks * 32 + (l >> 4) * 8 + e;
        wt2[idx] = __float2half(w[(size_t)(o * 64 + c) * 27 + kv]);
    }
}

// Fragment-direct deformable conv: no LDS / no barriers in the main loop.
// Wave = (n-tile of 16, z-plane of 9 taps). Lane l's sample registers ARE the
// MFMA B-fragment: ph=0 -> g=l>>4 (ks=0 k-slice), ph=1 -> g=4+(l>>4) (ks=1).
__global__ __launch_bounds__(192, 4) void dconv_kernel(const float* __restrict__ offset,
                                                       const __half* __restrict__ xt,
                                                       const __half* __restrict__ wt2,
                                                       float* __restrict__ out) {
    __shared__ float red_s[3][64][20];   // [chunk][o][n(+pad)] : 15.4 KB
    const int tid = threadIdx.x;
    const int lane = tid & 63;
    const int wv = tid >> 6;             // kv chunk = kernel z-plane (kz == wv)
    // bijective XCD swizzle: 1568 = 8*196, consecutive tiles share offset lines
    const int tile = (blockIdx.x & 7) * 196 + (blockIdx.x >> 3);
    const int n0 = tile * NT_;
    const int nl = lane & 15;
    const int n = n0 + nl;
    const int kv0 = wv * 9;
    const int kz = wv;                   // kv/9 for kv in this chunk

    // per-lane kv-invariant values
    const int zo = n / HW_;
    const int rem = n - zo * HW_;
    const int yo = rem / W_;
    const int xo = rem - yo * W_;
    const __half* xg[2];
    const float* ob[2];
#pragma unroll
    for (int ph = 0; ph < 2; ++ph) {
        const int g = ph * 4 + (lane >> 4);
        xg[ph] = xt + (size_t)g * (N_ * 8);
        ob[ph] = offset + (size_t)g * (KV_ * 3 * N_) + n;
    }

    f32x4 acc[4] = {};

    // offset prefetch (one kv ahead), nontemporal: don't evict xt from L2
    float oz[2], oy[2], ox[2];
#pragma unroll
    for (int ph = 0; ph < 2; ++ph) {
        const float* p = ob[ph] + (size_t)kv0 * 3 * N_;
        oz[ph] = __builtin_nontemporal_load(p);
        oy[ph] = __builtin_nontemporal_load(p + N_);
        ox[ph] = __builtin_nontemporal_load(p + 2 * N_);
    }

    for (int kvi = 0; kvi < 9; ++kvi) {
        const int kv = kv0 + kvi;
        const int ky = kvi / 3, kx = kvi % 3;

        float pz[2], py[2], px[2];
        if (kvi < 8) {
#pragma unroll
            for (int ph = 0; ph < 2; ++ph) {
                const float* p = ob[ph] + (size_t)(kv + 1) * 3 * N_;
                pz[ph] = __builtin_nontemporal_load(p);
                py[ph] = __builtin_nontemporal_load(p + N_);
                px[ph] = __builtin_nontemporal_load(p + 2 * N_);
            }
        }

        // ---- A-fragments for this kv: coalesced 16B/lane loads ----
        const __half* wb = wt2 + (size_t)kv * 4096 + lane * 8;
        f16x8 af[4][2];
#pragma unroll
        for (int of = 0; of < 4; ++of)
#pragma unroll
            for (int ks = 0; ks < 2; ++ks)
                af[of][ks] = *(const f16x8*)(wb + of * 1024 + ks * 512);

        // ---- sampling: build the two B-fragments in registers ----
        f16x8 bf[2];
#pragma unroll
        for (int ph = 0; ph < 2; ++ph) {
            float zc = (float)(zo + kz - 1) + oz[ph];
            float yc = (float)(yo + ky - 1) + oy[ph];
            float xc = (float)(xo + kx - 1) + ox[ph];
            float zf = floorf(zc), yf = floorf(yc), xf = floorf(xc);
            float dz = zc - zf, dy = yc - yf, dx = xc - xf;
            int z0 = (int)zf, y0 = (int)yf, x0 = (int)xf;
            int z1 = z0 + 1, y1 = y0 + 1, x1 = x0 + 1;
            float wz0 = (1.f - dz) * ((unsigned)z0 < (unsigned)D_ ? 1.f : 0.f);
            float wz1 = dz * ((unsigned)z1 < (unsigned)D_ ? 1.f : 0.f);
            float wy0 = (1.f - dy) * ((unsigned)y0 < (unsigned)H_ ? 1.f : 0.f);
            float wy1 = dy * ((unsigned)y1 < (unsigned)H_ ? 1.f : 0.f);
            float wx0 = (1.f - dx) * ((unsigned)x0 < (unsigned)W_ ? 1.f : 0.f);
            float wx1 = dx * ((unsigned)x1 < (unsigned)W_ ? 1.f : 0.f);
            int z0c = min(max(z0, 0), D_ - 1), z1c = min(max(z1, 0), D_ - 1);
            int y0c = min(max(y0, 0), H_ - 1), y1c = min(max(y1, 0), H_ - 1);
            int x0c = min(max(x0, 0), W_ - 1), x1c = min(max(x1, 0), W_ - 1);
            const uint4* xp = (const uint4*)xg[ph];
            int zy00 = z0c * HW_ + y0c * W_, zy01 = z0c * HW_ + y1c * W_;
            int zy10 = z1c * HW_ + y0c * W_, zy11 = z1c * HW_ + y1c * W_;
            U4H a; a.u = make_uint4(0u, 0u, 0u, 0u);
#define CORNER(ZY, XC, WF) do { \
                U4H d_; d_.u = xp[(ZY) + (XC)]; \
                __half2 w2_ = __float2half2_rn(WF); \
                a.h[0] = __hfma2(d_.h[0], w2_, a.h[0]); \
                a.h[1] = __hfma2(d_.h[1], w2_, a.h[1]); \
                a.h[2] = __hfma2(d_.h[2], w2_, a.h[2]); \
                a.h[3] = __hfma2(d_.h[3], w2_, a.h[3]); \
            } while (0)
            CORNER(zy00, x0c, wz0 * wy0 * wx0);
            CORNER(zy00, x1c, wz0 * wy0 * wx1);
            CORNER(zy01, x0c, wz0 * wy1 * wx0);
            CORNER(zy01, x1c, wz0 * wy1 * wx1);
            CORNER(zy10, x0c, wz1 * wy0 * wx0);
            CORNER(zy10, x1c, wz1 * wy0 * wx1);
            CORNER(zy11, x0c, wz1 * wy1 * wx0);
            CORNER(zy11, x1c, wz1 * wy1 * wx1);
#undef CORNER
            bf[ph] = a.v;
        }

        // ---- 8 MFMA: C[o][n] += w[o][c] * val[c][n], K=64 ----
#pragma unroll
        for (int of = 0; of < 4; ++of) {
            acc[of] = __builtin_amdgcn_mfma_f32_16x16x32_f16(af[of][0], bf[0], acc[of], 0, 0, 0);
            acc[of] = __builtin_amdgcn_mfma_f32_16x16x32_f16(af[of][1], bf[1], acc[of], 0, 0, 0);
        }

#pragma unroll
        for (int ph = 0; ph < 2; ++ph) { oz[ph] = pz[ph]; oy[ph] = py[ph]; ox[ph] = px[ph]; }
    }

    // ---- combine the 3 chunk-waves' C tiles (only sync in the kernel) ----
    // C layout: lane holds rows o = of*16 + (lane>>4)*4 + r, col n = lane&15.
#pragma unroll
    for (int of = 0; of < 4; ++of)
#pragma unroll
        for (int r = 0; r < 4; ++r)
            red_s[wv][of * 16 + (lane >> 4) * 4 + r][nl] = acc[of][r];
    __syncthreads();
#pragma unroll
    for (int e = tid; e < 256; e += 192) {
        const int o = e >> 2, n4 = (e & 3) * 4;
        f32x4 s = *(const f32x4*)&red_s[0][o][n4]
                + *(const f32x4*)&red_s[1][o][n4]
                + *(const f32x4*)&red_s[2][o][n4];
        *(f32x4*)(out + (size_t)o * N_ + n0 + n4) = s;
    }
}

extern "C" void kernel_launch(void* const* d_in, const int* in_sizes, int n_in,
                              void* d_out, int out_size, void* d_ws, size_t ws_size,
                              hipStream_t stream) {
    const float* x      = (const float*)d_in[0];
    const float* offset = (const float*)d_in[1];
    const float* weight = (const float*)d_in[2];
    float* out = (float*)d_out;

    __half* xt  = (__half*)d_ws;                 // 8*25088*8 halves = 3.2 MB
    __half* wt2 = xt + (size_t)8 * N_ * 8;       // 27*4096 halves = 216 KB

    prep_kernel<<<784 + 432, 256, 0, stream>>>(x, weight, xt, wt2);
    dconv_kernel<<<NTILES_, 192, 0, stream>>>(offset, xt, wt2, out);
}